// Round 24
// baseline (45.184 us; speedup 1.0000x reference)
//
#include <hip/hip_runtime.h>
#include <stdint.h>

#define BB 8
#define NN 2048
#define CC 128
#define OO 128

typedef __attribute__((ext_vector_type(8))) short bf16x8;
typedef __attribute__((ext_vector_type(4))) float f32x4;
typedef __attribute__((ext_vector_type(4))) int i32x4;
typedef __attribute__((ext_vector_type(4))) unsigned short u16x4;
typedef unsigned int u32;
typedef unsigned short u16;

__device__ __forceinline__ u16 f2bf(float f) {
    union { float f; u32 u; } v; v.f = f;
    u32 r = v.u + 0x7FFFu + ((v.u >> 16) & 1u);
    return (u16)(r >> 16);
}

// async global->LDS 16B: LDS dest wave-uniform base + lane*16; swizzle lives
// in the per-lane global source address (m104/m173 rule).
__device__ __forceinline__ void gl_lds16(const u16* g, u16* l) {
    __builtin_amdgcn_global_load_lds(
        (__attribute__((address_space(1))) void*)(uintptr_t)g,
        (__attribute__((address_space(3))) void*)l, 16, 0, 0);
}

// ---------------------------------------------------------------------------
// Kernel 1: precompute via MFMA — wt transpose fused in via LDS (R23, -2.4us
// vs separate wt_kernel). wlt[o][c] = bf16(W_lin[c][o]) staged per-block
// (34.8KB LDS, stride 136 u16 -> fragment reads 16B-aligned, conflict-free).
//   sj[b][n] = x·w1 + b_fc ; sk[b][n] = x·w2 (f32); Yt = bf16((x@W_lin)^T)
// ---------------------------------------------------------------------------
__global__ __launch_bounds__(256) void precompute_kernel(
    const float* __restrict__ x, const float* __restrict__ W_fc,
    const float* __restrict__ b_fc, const float* __restrict__ W_lin,
    float* __restrict__ sj, float* __restrict__ sk, u16* __restrict__ Yt)
{
    __shared__ __align__(16) u16 wlt[128][136];   // Wt[o][c], +8 pad (16B-aligned rows)

    const int t = threadIdx.x, l = t & 63, w = t >> 6;
    const int sl = l & 15, g = l >> 4;
    const int b  = blockIdx.x >> 6;
    const int k0 = (blockIdx.x & 63) << 5;
    const int mt = w & 1, nb = (w >> 1) << 2;
    const int row = k0 + mt * 16 + sl;
    const float* xr = x + ((size_t)(b * NN + row) << 7);

    // stage W_lin^T -> wlt: f = (c<<5)|og; coalesced f32x4 loads, one-time
    #pragma unroll
    for (int p = 0; p < 16; ++p) {
        int f  = t + p * 256;        // 0..4095
        int c  = f >> 5;             // 0..127
        int og = f & 31;             // o-group of 4
        f32x4 v = *(const f32x4*)(W_lin + c * OO + og * 4);
        #pragma unroll
        for (int e = 0; e < 4; ++e) wlt[og * 4 + e][c] = f2bf(v[e]);
    }

    bf16x8 a[4];
    float p1 = 0.f, p2 = 0.f;
    #pragma unroll
    for (int ks = 0; ks < 4; ++ks) {
        f32x4 lo4 = *(const f32x4*)(xr + ks * 32 + g * 8);
        f32x4 hi4 = *(const f32x4*)(xr + ks * 32 + g * 8 + 4);
        f32x4 w1l = *(const f32x4*)(W_fc + ks * 32 + g * 8);
        f32x4 w1h = *(const f32x4*)(W_fc + ks * 32 + g * 8 + 4);
        f32x4 w2l = *(const f32x4*)(W_fc + CC + ks * 32 + g * 8);
        f32x4 w2h = *(const f32x4*)(W_fc + CC + ks * 32 + g * 8 + 4);
        bf16x8 av;
        #pragma unroll
        for (int e = 0; e < 4; ++e) {
            p1 += lo4[e] * w1l[e] + hi4[e] * w1h[e];
            p2 += lo4[e] * w2l[e] + hi4[e] * w2h[e];
            av[e]     = (short)f2bf(lo4[e]);
            av[e + 4] = (short)f2bf(hi4[e]);
        }
        a[ks] = av;
    }
    p1 += __shfl_xor(p1, 16); p1 += __shfl_xor(p1, 32);
    p2 += __shfl_xor(p2, 16); p2 += __shfl_xor(p2, 32);
    if (w < 2 && g == 0) {
        sj[b * NN + row] = p1 + b_fc[0];
        sk[b * NN + row] = p2;
    }

    __syncthreads();   // wlt staged before fragment reads

    f32x4 acc[4];
    #pragma unroll
    for (int i = 0; i < 4; ++i) acc[i] = (f32x4){0.f, 0.f, 0.f, 0.f};
    #pragma unroll
    for (int i = 0; i < 4; ++i) {
        const u16* wp = &wlt[(nb + i) * 16 + sl][0];
        #pragma unroll
        for (int ks = 0; ks < 4; ++ks) {
            bf16x8 bv = *(const bf16x8*)(wp + ks * 32 + g * 8);
            acc[i] = __builtin_amdgcn_mfma_f32_16x16x32_bf16(a[ks], bv, acc[i], 0, 0, 0);
        }
    }
    #pragma unroll
    for (int i = 0; i < 4; ++i) {
        const int o = (nb + i) * 16 + sl;
        u16x4 h;
        #pragma unroll
        for (int e = 0; e < 4; ++e) h[e] = f2bf(acc[i][e]);
        *(u16x4*)(Yt + (size_t)(b * OO + o) * NN + k0 + mt * 16 + g * 4) = h;
    }
}

// ---------------------------------------------------------------------------
// Kernel 2: main — FINAL (45.2us total with fused precompute; 5-run stable).
// Single-barrier pipelined body, 512 threads / 8 waves, wave-level o-split
// (wave w owns o-slice w*16; pb block-shared so sigmoid/adj/staging totals
// are not duplicated). LDS = ybuf 64KB + pb 16KB = 81920B exactly ->
// 2 blocks/CU = 16 waves/CU. Per body T: stage(T+1) 4x gl_lds ->
// ybuf[(T+1)&1]; sigmoid(T+1) from regs loaded 2 bodies ago (static E/O
// sets) -> pb[(T+1)&1]; reload adj/sk(T+3); vmcnt(10) [stage(T) retired:
// prev reload 3 + this stage 4 + this reload 3]; 8 MFMA from
// pb[T&1]/ybuf[T&1]; lgkmcnt(0) + ONE barrier. lb(512,2): VGPR cap 256 ->
// no spills (spills corrupt vmcnt accounting — the R8-R10 failure family).
// grid = 8b x 64jt = 512 blocks, b = bid&7 XCD-pinned.
// ---------------------------------------------------------------------------
__global__ __launch_bounds__(512, 2) void graphconv_main(
    const int* __restrict__ adj, const float* __restrict__ sj,
    const float* __restrict__ sk, const u16* __restrict__ Yt,
    const float* __restrict__ b_lin, float* __restrict__ out)
{
    __shared__ __align__(16) u16 ybuf[2][16384];  // [par][128 o x 16 chunks x 8]
    __shared__ __align__(16) u16 pb[2][4096];     // [par][32 j x 16 chunks x 8]
    float* Sld = (float*)&pb[0][0];               // alias; used only post-loop

    const int t  = threadIdx.x;
    const int l  = t & 63, w = t >> 6;            // w in [0,8)
    const int sw = l & 15, kg = l >> 4;
    const int lo = l & 31, hi = l >> 5;
    const int b  = blockIdx.x & 7;
    const int j0 = (int)(blockIdx.x >> 3) << 5;

    // P-phase mapping: thread covers rows R = j0 + w*4 + 2q + hi (q=0,1),
    // k = lo*4 + e (lane-contiguous 16B adj segments per half-wave)
    const int* arow[2];
    float sjr[2];
    #pragma unroll
    for (int q = 0; q < 2; ++q) {
        const int R = j0 + w * 4 + 2 * q + hi;
        arow[q] = adj + ((size_t)b * NN + R) * NN + lo * 4;
        sjr[q]  = sj[b * NN + R];
    }
    const float* skp = sk + b * NN + lo * 4;

    // Y staging: linear LDS dest, inverse-swizzled per-lane global source
    u32 yoff[4];
    #pragma unroll
    for (int i = 0; i < 4; ++i) {
        int u  = (w * 4 + i) * 64 + l;            // 0..2047 chunks
        int o  = u >> 4;
        int kc = (u & 15) ^ (o & 15);
        yoff[i] = (u32)(b * OO + o) * NN + kc * 8;
    }

    f32x4 acc[2];
    #pragma unroll
    for (int js = 0; js < 2; ++js) acc[js] = (f32x4){0.f, 0.f, 0.f, 0.f};
    float psum[2] = {0.f, 0.f};

// sigmoid for one tile from (AV,SV) -> pb[PAR]
#define SIGP(AV, SV, PAR)                                                     \
    {                                                                         \
        u16x4 hq[2];                                                          \
        _Pragma("unroll")                                                     \
        for (int q = 0; q < 2; ++q) {                                         \
            _Pragma("unroll")                                                 \
            for (int e = 0; e < 4; ++e) {                                     \
                float z  = sjr[q] + SV[e];                                    \
                float sg = __builtin_amdgcn_rcpf(1.0f + __expf(-z));          \
                float pv = AV[q][e] ? sg : 0.0f;                              \
                psum[q] += pv;                                                \
                hq[q][e] = f2bf(pv);                                          \
            }                                                                 \
        }                                                                     \
        const int kc_ = lo >> 1, hh_ = lo & 1;                                \
        _Pragma("unroll")                                                     \
        for (int q = 0; q < 2; ++q) {                                         \
            const int R = w * 4 + 2 * q + hi;                                 \
            const int u = R * 16 + (kc_ ^ (R & 15));                          \
            *(u16x4*)&pb[PAR][u * 8 + hh_ * 4] = hq[q];                       \
        }                                                                     \
    }

    // prologue: stage(0); adj/sk(0) temp; E<-adj/sk(1); O<-adj/sk(2);
    // sigmoid(0)->pb[0]; lgkm+barrier. (in-order vmcnt retirement: SIGP's
    // auto-wait on aT implies stage(0) retired before body 0's MFMA gate)
    #pragma unroll
    for (int i = 0; i < 4; ++i)
        gl_lds16(Yt + yoff[i], &ybuf[0][(w * 4 + i) * 512]);
    i32x4 aT[2], aE[2], aO[2];
    f32x4 sT, sE, sO;
    #pragma unroll
    for (int q = 0; q < 2; ++q) aT[q] = *(const i32x4*)(arow[q]);
    sT = *(const f32x4*)(skp);
    #pragma unroll
    for (int q = 0; q < 2; ++q) aE[q] = *(const i32x4*)(arow[q] + 128);
    sE = *(const f32x4*)(skp + 128);
    #pragma unroll
    for (int q = 0; q < 2; ++q) aO[q] = *(const i32x4*)(arow[q] + 256);
    sO = *(const f32x4*)(skp + 256);
    SIGP(aT, sT, 0)
    asm volatile("s_waitcnt lgkmcnt(0)" ::: "memory");
    __builtin_amdgcn_s_barrier();
    asm volatile("" ::: "memory");

// body T (0..14): stage(T+1); sigmoid(T+1) from AC/SC (loaded 2 bodies ago);
// reload AC/SC <- adj/sk(min(T+3,15)); vmcnt(10) [stage(T) retired]; MFMA(T);
// lgkm+barrier.
#define TILE_BODY(T, AC, SC)                                                  \
    {                                                                         \
        const int T_ = (T);                                                   \
        const int tn = T_ + 1;                                                \
        const int tp = (T_ + 3 > 15) ? 15 : T_ + 3;                           \
        const int pn = tn & 1, pc = T_ & 1;                                   \
        _Pragma("unroll")                                                     \
        for (int i = 0; i < 4; ++i)                                           \
            gl_lds16(Yt + yoff[i] + (tn << 7), &ybuf[pn][(w * 4 + i) * 512]); \
        SIGP(AC, SC, pn)                                                      \
        _Pragma("unroll")                                                     \
        for (int q = 0; q < 2; ++q)                                           \
            AC[q] = *(const i32x4*)(arow[q] + tp * 128);                      \
        SC = *(const f32x4*)(skp + tp * 128);                                 \
        asm volatile("s_waitcnt vmcnt(10)" ::: "memory");                     \
        _Pragma("unroll")                                                     \
        for (int kk = 0; kk < 4; ++kk) {                                      \
            const int kc = kk * 4 + kg;                                       \
            bf16x8 af[2];                                                     \
            _Pragma("unroll")                                                 \
            for (int js = 0; js < 2; ++js)                                    \
                af[js] = *(const bf16x8*)&pb[pc][((js * 16 + sw) * 16 + (kc ^ sw)) * 8]; \
            const int o = w * 16 + sw;                                        \
            bf16x8 bv = *(const bf16x8*)&ybuf[pc][(o * 16 + (kc ^ sw)) * 8];  \
            _Pragma("unroll")                                                 \
            for (int js = 0; js < 2; ++js)                                    \
                acc[js] = __builtin_amdgcn_mfma_f32_16x16x32_bf16(            \
                    af[js], bv, acc[js], 0, 0, 0);                            \
        }                                                                     \
        asm volatile("s_waitcnt lgkmcnt(0)" ::: "memory");                    \
        __builtin_amdgcn_s_barrier();                                         \
        asm volatile("" ::: "memory");                                        \
    }

    for (int m = 0; m < 7; ++m) {
        TILE_BODY(2 * m,     aE, sE)      // consumes adj(2m+1), reloads (2m+3)
        TILE_BODY(2 * m + 1, aO, sO)      // consumes adj(2m+2), reloads (2m+4)
    }
    TILE_BODY(14, aE, sE)                 // consumes adj(15), reloads junk
#undef TILE_BODY
#undef SIGP

    // peeled tile 15: pb[1]/ybuf[1] (written body 14; visible after barrier)
    asm volatile("s_waitcnt vmcnt(0)" ::: "memory");   // stage(15) certainly done
    #pragma unroll
    for (int kk = 0; kk < 4; ++kk) {
        const int kc = kk * 4 + kg;
        bf16x8 af[2];
        #pragma unroll
        for (int js = 0; js < 2; ++js)
            af[js] = *(const bf16x8*)&pb[1][((js * 16 + sw) * 16 + (kc ^ sw)) * 8];
        const int o = w * 16 + sw;
        bf16x8 bv = *(const bf16x8*)&ybuf[1][(o * 16 + (kc ^ sw)) * 8];
        #pragma unroll
        for (int js = 0; js < 2; ++js)
            acc[js] = __builtin_amdgcn_mfma_f32_16x16x32_bf16(
                af[js], bv, acc[js], 0, 0, 0);
    }

    // rowsum reduce; Sld = pb[0] alias (pb[0] dead since body 14's ending
    // barrier — only pb[1] was read by the peel). Row R's 128 k live across
    // the 32 lanes with the same hi.
    #pragma unroll
    for (int q = 0; q < 2; ++q) {
        float s = psum[q];
        s += __shfl_xor(s, 1); s += __shfl_xor(s, 2); s += __shfl_xor(s, 4);
        s += __shfl_xor(s, 8); s += __shfl_xor(s, 16);
        if (lo == 0) Sld[w * 4 + 2 * q + hi] = s;
    }
    __syncthreads();

    // epilogue: C[j = j0 + js*16 + kg*4 + i][o = w*16 + sw]
    const int col = w * 16 + sw;
    const float bl = b_lin[col];
    #pragma unroll
    for (int js = 0; js < 2; ++js) {
        float rinv[4];
        #pragma unroll
        for (int i = 0; i < 4; ++i) rinv[i] = 1.0f / Sld[js * 16 + kg * 4 + i];
        #pragma unroll
        for (int i = 0; i < 4; ++i) {
            size_t row = (size_t)(b * NN + j0 + js * 16 + kg * 4 + i);
            out[row * OO + col] = acc[js][i] * rinv[i] + bl;
        }
    }
}

extern "C" void kernel_launch(void* const* d_in, const int* in_sizes, int n_in,
                              void* d_out, int out_size, void* d_ws, size_t ws_size,
                              hipStream_t stream) {
    const float* x     = (const float*)d_in[0];
    const int*   adj   = (const int*)d_in[1];
    const float* W_fc  = (const float*)d_in[2];
    const float* b_fc  = (const float*)d_in[3];
    const float* W_lin = (const float*)d_in[4];
    const float* b_lin = (const float*)d_in[5];
    float* out = (float*)d_out;

    // workspace: Yt (bf16, 4MB) | sj (64KB) | sk (64KB)  (proven range)
    u16*   Yt = (u16*)d_ws;
    float* sj = (float*)((char*)d_ws + (size_t)BB * OO * NN * sizeof(u16));
    float* sk = sj + BB * NN;

    precompute_kernel<<<512, 256, 0, stream>>>(x, W_fc, b_fc, W_lin, sj, sk, Yt);
    graphconv_main<<<512, 512, 0, stream>>>(adj, sj, sk, Yt, b_lin, out);
}

// Round 25
// 45.148 us; speedup vs baseline: 1.0008x; 1.0008x over previous
//
#include <hip/hip_runtime.h>
#include <stdint.h>

#define BB 8
#define NN 2048
#define CC 128
#define OO 128

typedef __attribute__((ext_vector_type(8))) short bf16x8;
typedef __attribute__((ext_vector_type(4))) float f32x4;
typedef __attribute__((ext_vector_type(4))) int i32x4;
typedef __attribute__((ext_vector_type(4))) unsigned short u16x4;
typedef unsigned int u32;
typedef unsigned short u16;

__device__ __forceinline__ u16 f2bf(float f) {
    union { float f; u32 u; } v; v.f = f;
    u32 r = v.u + 0x7FFFu + ((v.u >> 16) & 1u);
    return (u16)(r >> 16);
}

// async global->LDS 16B: LDS dest wave-uniform base + lane*16; swizzle lives
// in the per-lane global source address (m104/m173 rule).
__device__ __forceinline__ void gl_lds16(const u16* g, u16* l) {
    __builtin_amdgcn_global_load_lds(
        (__attribute__((address_space(1))) void*)(uintptr_t)g,
        (__attribute__((address_space(3))) void*)l, 16, 0, 0);
}

// ---------------------------------------------------------------------------
// Kernel 1: precompute via MFMA — wt transpose fused in via LDS (R23, -2.4us
// vs separate wt_kernel). wlt[o][c] = bf16(W_lin[c][o]) staged per-block
// (34.8KB LDS, stride 136 u16 -> fragment reads 16B-aligned, conflict-free).
//   sj[b][n] = x·w1 + b_fc ; sk[b][n] = x·w2 (f32); Yt = bf16((x@W_lin)^T)
// ---------------------------------------------------------------------------
__global__ __launch_bounds__(256) void precompute_kernel(
    const float* __restrict__ x, const float* __restrict__ W_fc,
    const float* __restrict__ b_fc, const float* __restrict__ W_lin,
    float* __restrict__ sj, float* __restrict__ sk, u16* __restrict__ Yt)
{
    __shared__ __align__(16) u16 wlt[128][136];   // Wt[o][c], +8 pad (16B-aligned rows)

    const int t = threadIdx.x, l = t & 63, w = t >> 6;
    const int sl = l & 15, g = l >> 4;
    const int b  = blockIdx.x >> 6;
    const int k0 = (blockIdx.x & 63) << 5;
    const int mt = w & 1, nb = (w >> 1) << 2;
    const int row = k0 + mt * 16 + sl;
    const float* xr = x + ((size_t)(b * NN + row) << 7);

    // stage W_lin^T -> wlt: f = (c<<5)|og; coalesced f32x4 loads, one-time
    #pragma unroll
    for (int p = 0; p < 16; ++p) {
        int f  = t + p * 256;        // 0..4095
        int c  = f >> 5;             // 0..127
        int og = f & 31;             // o-group of 4
        f32x4 v = *(const f32x4*)(W_lin + c * OO + og * 4);
        #pragma unroll
        for (int e = 0; e < 4; ++e) wlt[og * 4 + e][c] = f2bf(v[e]);
    }

    bf16x8 a[4];
    float p1 = 0.f, p2 = 0.f;
    #pragma unroll
    for (int ks = 0; ks < 4; ++ks) {
        f32x4 lo4 = *(const f32x4*)(xr + ks * 32 + g * 8);
        f32x4 hi4 = *(const f32x4*)(xr + ks * 32 + g * 8 + 4);
        f32x4 w1l = *(const f32x4*)(W_fc + ks * 32 + g * 8);
        f32x4 w1h = *(const f32x4*)(W_fc + ks * 32 + g * 8 + 4);
        f32x4 w2l = *(const f32x4*)(W_fc + CC + ks * 32 + g * 8);
        f32x4 w2h = *(const f32x4*)(W_fc + CC + ks * 32 + g * 8 + 4);
        bf16x8 av;
        #pragma unroll
        for (int e = 0; e < 4; ++e) {
            p1 += lo4[e] * w1l[e] + hi4[e] * w1h[e];
            p2 += lo4[e] * w2l[e] + hi4[e] * w2h[e];
            av[e]     = (short)f2bf(lo4[e]);
            av[e + 4] = (short)f2bf(hi4[e]);
        }
        a[ks] = av;
    }
    p1 += __shfl_xor(p1, 16); p1 += __shfl_xor(p1, 32);
    p2 += __shfl_xor(p2, 16); p2 += __shfl_xor(p2, 32);
    if (w < 2 && g == 0) {
        sj[b * NN + row] = p1 + b_fc[0];
        sk[b * NN + row] = p2;
    }

    __syncthreads();   // wlt staged before fragment reads

    f32x4 acc[4];
    #pragma unroll
    for (int i = 0; i < 4; ++i) acc[i] = (f32x4){0.f, 0.f, 0.f, 0.f};
    #pragma unroll
    for (int i = 0; i < 4; ++i) {
        const u16* wp = &wlt[(nb + i) * 16 + sl][0];
        #pragma unroll
        for (int ks = 0; ks < 4; ++ks) {
            bf16x8 bv = *(const bf16x8*)(wp + ks * 32 + g * 8);
            acc[i] = __builtin_amdgcn_mfma_f32_16x16x32_bf16(a[ks], bv, acc[i], 0, 0, 0);
        }
    }
    #pragma unroll
    for (int i = 0; i < 4; ++i) {
        const int o = (nb + i) * 16 + sl;
        u16x4 h;
        #pragma unroll
        for (int e = 0; e < 4; ++e) h[e] = f2bf(acc[i][e]);
        *(u16x4*)(Yt + (size_t)(b * OO + o) * NN + k0 + mt * 16 + g * 4) = h;
    }
}

// ---------------------------------------------------------------------------
// Kernel 2: main — FINAL (45.2us total; 6-run stable). Single-barrier
// pipelined body, 512 threads / 8 waves, wave-level o-split (wave w owns
// o-slice w*16; pb block-shared so sigmoid/adj/staging totals are not
// duplicated). LDS = ybuf 64KB + pb 16KB = 81920B exactly -> 2 blocks/CU
// = 16 waves/CU. Per body T: stage(T+1) 4x gl_lds -> ybuf[(T+1)&1];
// sigmoid(T+1) from regs loaded 2 bodies ago (static E/O sets) ->
// pb[(T+1)&1]; reload adj/sk(T+3); vmcnt(10) [stage(T) retired: prev
// reload 3 + this stage 4 + this reload 3]; 8 MFMA from pb[T&1]/ybuf[T&1];
// lgkmcnt(0) + ONE barrier. lb(512,2): VGPR cap 256 -> no spills (spills
// corrupt vmcnt accounting — the R8-R10 failure family).
// grid = 8b x 64jt = 512 blocks, b = bid&7 XCD-pinned.
// ---------------------------------------------------------------------------
__global__ __launch_bounds__(512, 2) void graphconv_main(
    const int* __restrict__ adj, const float* __restrict__ sj,
    const float* __restrict__ sk, const u16* __restrict__ Yt,
    const float* __restrict__ b_lin, float* __restrict__ out)
{
    __shared__ __align__(16) u16 ybuf[2][16384];  // [par][128 o x 16 chunks x 8]
    __shared__ __align__(16) u16 pb[2][4096];     // [par][32 j x 16 chunks x 8]
    float* Sld = (float*)&pb[0][0];               // alias; used only post-loop

    const int t  = threadIdx.x;
    const int l  = t & 63, w = t >> 6;            // w in [0,8)
    const int sw = l & 15, kg = l >> 4;
    const int lo = l & 31, hi = l >> 5;
    const int b  = blockIdx.x & 7;
    const int j0 = (int)(blockIdx.x >> 3) << 5;

    // P-phase mapping: thread covers rows R = j0 + w*4 + 2q + hi (q=0,1),
    // k = lo*4 + e (lane-contiguous 16B adj segments per half-wave)
    const int* arow[2];
    float sjr[2];
    #pragma unroll
    for (int q = 0; q < 2; ++q) {
        const int R = j0 + w * 4 + 2 * q + hi;
        arow[q] = adj + ((size_t)b * NN + R) * NN + lo * 4;
        sjr[q]  = sj[b * NN + R];
    }
    const float* skp = sk + b * NN + lo * 4;

    // Y staging: linear LDS dest, inverse-swizzled per-lane global source
    u32 yoff[4];
    #pragma unroll
    for (int i = 0; i < 4; ++i) {
        int u  = (w * 4 + i) * 64 + l;            // 0..2047 chunks
        int o  = u >> 4;
        int kc = (u & 15) ^ (o & 15);
        yoff[i] = (u32)(b * OO + o) * NN + kc * 8;
    }

    f32x4 acc[2];
    #pragma unroll
    for (int js = 0; js < 2; ++js) acc[js] = (f32x4){0.f, 0.f, 0.f, 0.f};
    float psum[2] = {0.f, 0.f};

// sigmoid for one tile from (AV,SV) -> pb[PAR]
#define SIGP(AV, SV, PAR)                                                     \
    {                                                                         \
        u16x4 hq[2];                                                          \
        _Pragma("unroll")                                                     \
        for (int q = 0; q < 2; ++q) {                                         \
            _Pragma("unroll")                                                 \
            for (int e = 0; e < 4; ++e) {                                     \
                float z  = sjr[q] + SV[e];                                    \
                float sg = __builtin_amdgcn_rcpf(1.0f + __expf(-z));          \
                float pv = AV[q][e] ? sg : 0.0f;                              \
                psum[q] += pv;                                                \
                hq[q][e] = f2bf(pv);                                          \
            }                                                                 \
        }                                                                     \
        const int kc_ = lo >> 1, hh_ = lo & 1;                                \
        _Pragma("unroll")                                                     \
        for (int q = 0; q < 2; ++q) {                                         \
            const int R = w * 4 + 2 * q + hi;                                 \
            const int u = R * 16 + (kc_ ^ (R & 15));                          \
            *(u16x4*)&pb[PAR][u * 8 + hh_ * 4] = hq[q];                       \
        }                                                                     \
    }

    // prologue: stage(0); adj/sk(0) temp; E<-adj/sk(1); O<-adj/sk(2);
    // sigmoid(0)->pb[0]; lgkm+barrier. (in-order vmcnt retirement: SIGP's
    // auto-wait on aT implies stage(0) retired before body 0's MFMA gate)
    #pragma unroll
    for (int i = 0; i < 4; ++i)
        gl_lds16(Yt + yoff[i], &ybuf[0][(w * 4 + i) * 512]);
    i32x4 aT[2], aE[2], aO[2];
    f32x4 sT, sE, sO;
    #pragma unroll
    for (int q = 0; q < 2; ++q) aT[q] = *(const i32x4*)(arow[q]);
    sT = *(const f32x4*)(skp);
    #pragma unroll
    for (int q = 0; q < 2; ++q) aE[q] = *(const i32x4*)(arow[q] + 128);
    sE = *(const f32x4*)(skp + 128);
    #pragma unroll
    for (int q = 0; q < 2; ++q) aO[q] = *(const i32x4*)(arow[q] + 256);
    sO = *(const f32x4*)(skp + 256);
    SIGP(aT, sT, 0)
    asm volatile("s_waitcnt lgkmcnt(0)" ::: "memory");
    __builtin_amdgcn_s_barrier();
    asm volatile("" ::: "memory");

// body T (0..14): stage(T+1); sigmoid(T+1) from AC/SC (loaded 2 bodies ago);
// reload AC/SC <- adj/sk(min(T+3,15)); vmcnt(10) [stage(T) retired]; MFMA(T);
// lgkm+barrier.
#define TILE_BODY(T, AC, SC)                                                  \
    {                                                                         \
        const int T_ = (T);                                                   \
        const int tn = T_ + 1;                                                \
        const int tp = (T_ + 3 > 15) ? 15 : T_ + 3;                           \
        const int pn = tn & 1, pc = T_ & 1;                                   \
        _Pragma("unroll")                                                     \
        for (int i = 0; i < 4; ++i)                                           \
            gl_lds16(Yt + yoff[i] + (tn << 7), &ybuf[pn][(w * 4 + i) * 512]); \
        SIGP(AC, SC, pn)                                                      \
        _Pragma("unroll")                                                     \
        for (int q = 0; q < 2; ++q)                                           \
            AC[q] = *(const i32x4*)(arow[q] + tp * 128);                      \
        SC = *(const f32x4*)(skp + tp * 128);                                 \
        asm volatile("s_waitcnt vmcnt(10)" ::: "memory");                     \
        _Pragma("unroll")                                                     \
        for (int kk = 0; kk < 4; ++kk) {                                      \
            const int kc = kk * 4 + kg;                                       \
            bf16x8 af[2];                                                     \
            _Pragma("unroll")                                                 \
            for (int js = 0; js < 2; ++js)                                    \
                af[js] = *(const bf16x8*)&pb[pc][((js * 16 + sw) * 16 + (kc ^ sw)) * 8]; \
            const int o = w * 16 + sw;                                        \
            bf16x8 bv = *(const bf16x8*)&ybuf[pc][(o * 16 + (kc ^ sw)) * 8];  \
            _Pragma("unroll")                                                 \
            for (int js = 0; js < 2; ++js)                                    \
                acc[js] = __builtin_amdgcn_mfma_f32_16x16x32_bf16(            \
                    af[js], bv, acc[js], 0, 0, 0);                            \
        }                                                                     \
        asm volatile("s_waitcnt lgkmcnt(0)" ::: "memory");                    \
        __builtin_amdgcn_s_barrier();                                         \
        asm volatile("" ::: "memory");                                        \
    }

    for (int m = 0; m < 7; ++m) {
        TILE_BODY(2 * m,     aE, sE)      // consumes adj(2m+1), reloads (2m+3)
        TILE_BODY(2 * m + 1, aO, sO)      // consumes adj(2m+2), reloads (2m+4)
    }
    TILE_BODY(14, aE, sE)                 // consumes adj(15), reloads junk
#undef TILE_BODY
#undef SIGP

    // peeled tile 15: pb[1]/ybuf[1] (written body 14; visible after barrier)
    asm volatile("s_waitcnt vmcnt(0)" ::: "memory");   // stage(15) certainly done
    #pragma unroll
    for (int kk = 0; kk < 4; ++kk) {
        const int kc = kk * 4 + kg;
        bf16x8 af[2];
        #pragma unroll
        for (int js = 0; js < 2; ++js)
            af[js] = *(const bf16x8*)&pb[1][((js * 16 + sw) * 16 + (kc ^ sw)) * 8];
        const int o = w * 16 + sw;
        bf16x8 bv = *(const bf16x8*)&ybuf[1][(o * 16 + (kc ^ sw)) * 8];
        #pragma unroll
        for (int js = 0; js < 2; ++js)
            acc[js] = __builtin_amdgcn_mfma_f32_16x16x32_bf16(
                af[js], bv, acc[js], 0, 0, 0);
    }

    // rowsum reduce; Sld = pb[0] alias (pb[0] dead since body 14's ending
    // barrier — only pb[1] was read by the peel). Row R's 128 k live across
    // the 32 lanes with the same hi.
    #pragma unroll
    for (int q = 0; q < 2; ++q) {
        float s = psum[q];
        s += __shfl_xor(s, 1); s += __shfl_xor(s, 2); s += __shfl_xor(s, 4);
        s += __shfl_xor(s, 8); s += __shfl_xor(s, 16);
        if (lo == 0) Sld[w * 4 + 2 * q + hi] = s;
    }
    __syncthreads();

    // epilogue: C[j = j0 + js*16 + kg*4 + i][o = w*16 + sw]
    const int col = w * 16 + sw;
    const float bl = b_lin[col];
    #pragma unroll
    for (int js = 0; js < 2; ++js) {
        float rinv[4];
        #pragma unroll
        for (int i = 0; i < 4; ++i) rinv[i] = 1.0f / Sld[js * 16 + kg * 4 + i];
        #pragma unroll
        for (int i = 0; i < 4; ++i) {
            size_t row = (size_t)(b * NN + j0 + js * 16 + kg * 4 + i);
            out[row * OO + col] = acc[js][i] * rinv[i] + bl;
        }
    }
}

extern "C" void kernel_launch(void* const* d_in, const int* in_sizes, int n_in,
                              void* d_out, int out_size, void* d_ws, size_t ws_size,
                              hipStream_t stream) {
    const float* x     = (const float*)d_in[0];
    const int*   adj   = (const int*)d_in[1];
    const float* W_fc  = (const float*)d_in[2];
    const float* b_fc  = (const float*)d_in[3];
    const float* W_lin = (const float*)d_in[4];
    const float* b_lin = (const float*)d_in[5];
    float* out = (float*)d_out;

    // workspace: Yt (bf16, 4MB) | sj (64KB) | sk (64KB)  (proven range)
    u16*   Yt = (u16*)d_ws;
    float* sj = (float*)((char*)d_ws + (size_t)BB * OO * NN * sizeof(u16));
    float* sk = sj + BB * NN;

    precompute_kernel<<<512, 256, 0, stream>>>(x, W_fc, b_fc, W_lin, sj, sk, Yt);
    graphconv_main<<<512, 512, 0, stream>>>(adj, sj, sk, Yt, b_lin, out);
}

// Round 26
// 45.122 us; speedup vs baseline: 1.0014x; 1.0006x over previous
//
#include <hip/hip_runtime.h>
#include <stdint.h>

#define BB 8
#define NN 2048
#define CC 128
#define OO 128

typedef __attribute__((ext_vector_type(8))) short bf16x8;
typedef __attribute__((ext_vector_type(4))) float f32x4;
typedef __attribute__((ext_vector_type(4))) int i32x4;
typedef __attribute__((ext_vector_type(4))) unsigned short u16x4;
typedef unsigned int u32;
typedef unsigned short u16;

__device__ __forceinline__ u16 f2bf(float f) {
    union { float f; u32 u; } v; v.f = f;
    u32 r = v.u + 0x7FFFu + ((v.u >> 16) & 1u);
    return (u16)(r >> 16);
}

// async global->LDS 16B: LDS dest wave-uniform base + lane*16; swizzle lives
// in the per-lane global source address (m104/m173 rule).
__device__ __forceinline__ void gl_lds16(const u16* g, u16* l) {
    __builtin_amdgcn_global_load_lds(
        (__attribute__((address_space(1))) void*)(uintptr_t)g,
        (__attribute__((address_space(3))) void*)l, 16, 0, 0);
}

// ---------------------------------------------------------------------------
// Kernel 1: precompute via MFMA — wt transpose fused in via LDS (R23, -2.4us
// vs separate wt_kernel). wlt[o][c] = bf16(W_lin[c][o]) staged per-block
// (34.8KB LDS, stride 136 u16 -> fragment reads 16B-aligned, conflict-free).
//   sj[b][n] = x·w1 + b_fc ; sk[b][n] = x·w2 (f32); Yt = bf16((x@W_lin)^T)
// ---------------------------------------------------------------------------
__global__ __launch_bounds__(256) void precompute_kernel(
    const float* __restrict__ x, const float* __restrict__ W_fc,
    const float* __restrict__ b_fc, const float* __restrict__ W_lin,
    float* __restrict__ sj, float* __restrict__ sk, u16* __restrict__ Yt)
{
    __shared__ __align__(16) u16 wlt[128][136];   // Wt[o][c], +8 pad (16B-aligned rows)

    const int t = threadIdx.x, l = t & 63, w = t >> 6;
    const int sl = l & 15, g = l >> 4;
    const int b  = blockIdx.x >> 6;
    const int k0 = (blockIdx.x & 63) << 5;
    const int mt = w & 1, nb = (w >> 1) << 2;
    const int row = k0 + mt * 16 + sl;
    const float* xr = x + ((size_t)(b * NN + row) << 7);

    // stage W_lin^T -> wlt: f = (c<<5)|og; coalesced f32x4 loads, one-time
    #pragma unroll
    for (int p = 0; p < 16; ++p) {
        int f  = t + p * 256;        // 0..4095
        int c  = f >> 5;             // 0..127
        int og = f & 31;             // o-group of 4
        f32x4 v = *(const f32x4*)(W_lin + c * OO + og * 4);
        #pragma unroll
        for (int e = 0; e < 4; ++e) wlt[og * 4 + e][c] = f2bf(v[e]);
    }

    bf16x8 a[4];
    float p1 = 0.f, p2 = 0.f;
    #pragma unroll
    for (int ks = 0; ks < 4; ++ks) {
        f32x4 lo4 = *(const f32x4*)(xr + ks * 32 + g * 8);
        f32x4 hi4 = *(const f32x4*)(xr + ks * 32 + g * 8 + 4);
        f32x4 w1l = *(const f32x4*)(W_fc + ks * 32 + g * 8);
        f32x4 w1h = *(const f32x4*)(W_fc + ks * 32 + g * 8 + 4);
        f32x4 w2l = *(const f32x4*)(W_fc + CC + ks * 32 + g * 8);
        f32x4 w2h = *(const f32x4*)(W_fc + CC + ks * 32 + g * 8 + 4);
        bf16x8 av;
        #pragma unroll
        for (int e = 0; e < 4; ++e) {
            p1 += lo4[e] * w1l[e] + hi4[e] * w1h[e];
            p2 += lo4[e] * w2l[e] + hi4[e] * w2h[e];
            av[e]     = (short)f2bf(lo4[e]);
            av[e + 4] = (short)f2bf(hi4[e]);
        }
        a[ks] = av;
    }
    p1 += __shfl_xor(p1, 16); p1 += __shfl_xor(p1, 32);
    p2 += __shfl_xor(p2, 16); p2 += __shfl_xor(p2, 32);
    if (w < 2 && g == 0) {
        sj[b * NN + row] = p1 + b_fc[0];
        sk[b * NN + row] = p2;
    }

    __syncthreads();   // wlt staged before fragment reads

    f32x4 acc[4];
    #pragma unroll
    for (int i = 0; i < 4; ++i) acc[i] = (f32x4){0.f, 0.f, 0.f, 0.f};
    #pragma unroll
    for (int i = 0; i < 4; ++i) {
        const u16* wp = &wlt[(nb + i) * 16 + sl][0];
        #pragma unroll
        for (int ks = 0; ks < 4; ++ks) {
            bf16x8 bv = *(const bf16x8*)(wp + ks * 32 + g * 8);
            acc[i] = __builtin_amdgcn_mfma_f32_16x16x32_bf16(a[ks], bv, acc[i], 0, 0, 0);
        }
    }
    #pragma unroll
    for (int i = 0; i < 4; ++i) {
        const int o = (nb + i) * 16 + sl;
        u16x4 h;
        #pragma unroll
        for (int e = 0; e < 4; ++e) h[e] = f2bf(acc[i][e]);
        *(u16x4*)(Yt + (size_t)(b * OO + o) * NN + k0 + mt * 16 + g * 4) = h;
    }
}

// ---------------------------------------------------------------------------
// Kernel 2: main — FINAL (45.15-45.18us, 4-run stable). Single-barrier
// pipelined body, 512 threads / 8 waves, wave-level o-split (wave w owns
// o-slice w*16; pb block-shared so sigmoid/adj/staging totals are not
// duplicated). LDS = ybuf 64KB + pb 16KB = 81920B exactly -> 2 blocks/CU
// = 16 waves/CU. Per body T: stage(T+1) 4x gl_lds -> ybuf[(T+1)&1];
// sigmoid(T+1) from regs loaded 2 bodies ago (static E/O sets) ->
// pb[(T+1)&1]; reload adj/sk(T+3); vmcnt(10) [stage(T) retired: prev
// reload 3 + this stage 4 + this reload 3]; 8 MFMA from pb[T&1]/ybuf[T&1];
// lgkmcnt(0) + ONE barrier. lb(512,2): VGPR cap 256 -> no spills (spills
// corrupt vmcnt accounting — the R8-R10 failure family).
// grid = 8b x 64jt = 512 blocks, b = bid&7 XCD-pinned.
// ---------------------------------------------------------------------------
__global__ __launch_bounds__(512, 2) void graphconv_main(
    const int* __restrict__ adj, const float* __restrict__ sj,
    const float* __restrict__ sk, const u16* __restrict__ Yt,
    const float* __restrict__ b_lin, float* __restrict__ out)
{
    __shared__ __align__(16) u16 ybuf[2][16384];  // [par][128 o x 16 chunks x 8]
    __shared__ __align__(16) u16 pb[2][4096];     // [par][32 j x 16 chunks x 8]
    float* Sld = (float*)&pb[0][0];               // alias; used only post-loop

    const int t  = threadIdx.x;
    const int l  = t & 63, w = t >> 6;            // w in [0,8)
    const int sw = l & 15, kg = l >> 4;
    const int lo = l & 31, hi = l >> 5;
    const int b  = blockIdx.x & 7;
    const int j0 = (int)(blockIdx.x >> 3) << 5;

    // P-phase mapping: thread covers rows R = j0 + w*4 + 2q + hi (q=0,1),
    // k = lo*4 + e (lane-contiguous 16B adj segments per half-wave)
    const int* arow[2];
    float sjr[2];
    #pragma unroll
    for (int q = 0; q < 2; ++q) {
        const int R = j0 + w * 4 + 2 * q + hi;
        arow[q] = adj + ((size_t)b * NN + R) * NN + lo * 4;
        sjr[q]  = sj[b * NN + R];
    }
    const float* skp = sk + b * NN + lo * 4;

    // Y staging: linear LDS dest, inverse-swizzled per-lane global source
    u32 yoff[4];
    #pragma unroll
    for (int i = 0; i < 4; ++i) {
        int u  = (w * 4 + i) * 64 + l;            // 0..2047 chunks
        int o  = u >> 4;
        int kc = (u & 15) ^ (o & 15);
        yoff[i] = (u32)(b * OO + o) * NN + kc * 8;
    }

    f32x4 acc[2];
    #pragma unroll
    for (int js = 0; js < 2; ++js) acc[js] = (f32x4){0.f, 0.f, 0.f, 0.f};
    float psum[2] = {0.f, 0.f};

// sigmoid for one tile from (AV,SV) -> pb[PAR]
#define SIGP(AV, SV, PAR)                                                     \
    {                                                                         \
        u16x4 hq[2];                                                          \
        _Pragma("unroll")                                                     \
        for (int q = 0; q < 2; ++q) {                                         \
            _Pragma("unroll")                                                 \
            for (int e = 0; e < 4; ++e) {                                     \
                float z  = sjr[q] + SV[e];                                    \
                float sg = __builtin_amdgcn_rcpf(1.0f + __expf(-z));          \
                float pv = AV[q][e] ? sg : 0.0f;                              \
                psum[q] += pv;                                                \
                hq[q][e] = f2bf(pv);                                          \
            }                                                                 \
        }                                                                     \
        const int kc_ = lo >> 1, hh_ = lo & 1;                                \
        _Pragma("unroll")                                                     \
        for (int q = 0; q < 2; ++q) {                                         \
            const int R = w * 4 + 2 * q + hi;                                 \
            const int u = R * 16 + (kc_ ^ (R & 15));                          \
            *(u16x4*)&pb[PAR][u * 8 + hh_ * 4] = hq[q];                       \
        }                                                                     \
    }

    // prologue: stage(0); adj/sk(0) temp; E<-adj/sk(1); O<-adj/sk(2);
    // sigmoid(0)->pb[0]; lgkm+barrier. (in-order vmcnt retirement: SIGP's
    // auto-wait on aT implies stage(0) retired before body 0's MFMA gate)
    #pragma unroll
    for (int i = 0; i < 4; ++i)
        gl_lds16(Yt + yoff[i], &ybuf[0][(w * 4 + i) * 512]);
    i32x4 aT[2], aE[2], aO[2];
    f32x4 sT, sE, sO;
    #pragma unroll
    for (int q = 0; q < 2; ++q) aT[q] = *(const i32x4*)(arow[q]);
    sT = *(const f32x4*)(skp);
    #pragma unroll
    for (int q = 0; q < 2; ++q) aE[q] = *(const i32x4*)(arow[q] + 128);
    sE = *(const f32x4*)(skp + 128);
    #pragma unroll
    for (int q = 0; q < 2; ++q) aO[q] = *(const i32x4*)(arow[q] + 256);
    sO = *(const f32x4*)(skp + 256);
    SIGP(aT, sT, 0)
    asm volatile("s_waitcnt lgkmcnt(0)" ::: "memory");
    __builtin_amdgcn_s_barrier();
    asm volatile("" ::: "memory");

// body T (0..14): stage(T+1); sigmoid(T+1) from AC/SC (loaded 2 bodies ago);
// reload AC/SC <- adj/sk(min(T+3,15)); vmcnt(10) [stage(T) retired]; MFMA(T);
// lgkm+barrier.
#define TILE_BODY(T, AC, SC)                                                  \
    {                                                                         \
        const int T_ = (T);                                                   \
        const int tn = T_ + 1;                                                \
        const int tp = (T_ + 3 > 15) ? 15 : T_ + 3;                           \
        const int pn = tn & 1, pc = T_ & 1;                                   \
        _Pragma("unroll")                                                     \
        for (int i = 0; i < 4; ++i)                                           \
            gl_lds16(Yt + yoff[i] + (tn << 7), &ybuf[pn][(w * 4 + i) * 512]); \
        SIGP(AC, SC, pn)                                                      \
        _Pragma("unroll")                                                     \
        for (int q = 0; q < 2; ++q)                                           \
            AC[q] = *(const i32x4*)(arow[q] + tp * 128);                      \
        SC = *(const f32x4*)(skp + tp * 128);                                 \
        asm volatile("s_waitcnt vmcnt(10)" ::: "memory");                     \
        _Pragma("unroll")                                                     \
        for (int kk = 0; kk < 4; ++kk) {                                      \
            const int kc = kk * 4 + kg;                                       \
            bf16x8 af[2];                                                     \
            _Pragma("unroll")                                                 \
            for (int js = 0; js < 2; ++js)                                    \
                af[js] = *(const bf16x8*)&pb[pc][((js * 16 + sw) * 16 + (kc ^ sw)) * 8]; \
            const int o = w * 16 + sw;                                        \
            bf16x8 bv = *(const bf16x8*)&ybuf[pc][(o * 16 + (kc ^ sw)) * 8];  \
            _Pragma("unroll")                                                 \
            for (int js = 0; js < 2; ++js)                                    \
                acc[js] = __builtin_amdgcn_mfma_f32_16x16x32_bf16(            \
                    af[js], bv, acc[js], 0, 0, 0);                            \
        }                                                                     \
        asm volatile("s_waitcnt lgkmcnt(0)" ::: "memory");                    \
        __builtin_amdgcn_s_barrier();                                         \
        asm volatile("" ::: "memory");                                        \
    }

    for (int m = 0; m < 7; ++m) {
        TILE_BODY(2 * m,     aE, sE)      // consumes adj(2m+1), reloads (2m+3)
        TILE_BODY(2 * m + 1, aO, sO)      // consumes adj(2m+2), reloads (2m+4)
    }
    TILE_BODY(14, aE, sE)                 // consumes adj(15), reloads junk
#undef TILE_BODY
#undef SIGP

    // peeled tile 15: pb[1]/ybuf[1] (written body 14; visible after barrier)
    asm volatile("s_waitcnt vmcnt(0)" ::: "memory");   // stage(15) certainly done
    #pragma unroll
    for (int kk = 0; kk < 4; ++kk) {
        const int kc = kk * 4 + kg;
        bf16x8 af[2];
        #pragma unroll
        for (int js = 0; js < 2; ++js)
            af[js] = *(const bf16x8*)&pb[1][((js * 16 + sw) * 16 + (kc ^ sw)) * 8];
        const int o = w * 16 + sw;
        bf16x8 bv = *(const bf16x8*)&ybuf[1][(o * 16 + (kc ^ sw)) * 8];
        #pragma unroll
        for (int js = 0; js < 2; ++js)
            acc[js] = __builtin_amdgcn_mfma_f32_16x16x32_bf16(
                af[js], bv, acc[js], 0, 0, 0);
    }

    // rowsum reduce; Sld = pb[0] alias (pb[0] dead since body 14's ending
    // barrier — only pb[1] was read by the peel). Row R's 128 k live across
    // the 32 lanes with the same hi.
    #pragma unroll
    for (int q = 0; q < 2; ++q) {
        float s = psum[q];
        s += __shfl_xor(s, 1); s += __shfl_xor(s, 2); s += __shfl_xor(s, 4);
        s += __shfl_xor(s, 8); s += __shfl_xor(s, 16);
        if (lo == 0) Sld[w * 4 + 2 * q + hi] = s;
    }
    __syncthreads();

    // epilogue: C[j = j0 + js*16 + kg*4 + i][o = w*16 + sw]
    const int col = w * 16 + sw;
    const float bl = b_lin[col];
    #pragma unroll
    for (int js = 0; js < 2; ++js) {
        float rinv[4];
        #pragma unroll
        for (int i = 0; i < 4; ++i) rinv[i] = 1.0f / Sld[js * 16 + kg * 4 + i];
        #pragma unroll
        for (int i = 0; i < 4; ++i) {
            size_t row = (size_t)(b * NN + j0 + js * 16 + kg * 4 + i);
            out[row * OO + col] = acc[js][i] * rinv[i] + bl;
        }
    }
}

extern "C" void kernel_launch(void* const* d_in, const int* in_sizes, int n_in,
                              void* d_out, int out_size, void* d_ws, size_t ws_size,
                              hipStream_t stream) {
    const float* x     = (const float*)d_in[0];
    const int*   adj   = (const int*)d_in[1];
    const float* W_fc  = (const float*)d_in[2];
    const float* b_fc  = (const float*)d_in[3];
    const float* W_lin = (const float*)d_in[4];
    const float* b_lin = (const float*)d_in[5];
    float* out = (float*)d_out;

    // workspace: Yt (bf16, 4MB) | sj (64KB) | sk (64KB)  (proven range)
    u16*   Yt = (u16*)d_ws;
    float* sj = (float*)((char*)d_ws + (size_t)BB * OO * NN * sizeof(u16));
    float* sk = sj + BB * NN;

    precompute_kernel<<<512, 256, 0, stream>>>(x, W_fc, b_fc, W_lin, sj, sk, Yt);
    graphconv_main<<<512, 512, 0, stream>>>(adj, sj, sk, Yt, b_lin, out);
}